// Round 3
// baseline (294.521 us; speedup 1.0000x reference)
//
#include <hip/hip_runtime.h>
#include <hip/hip_bf16.h>

// HypoNerf fused MLP on MI355X (gfx950). R3:
//  - MT=64, 4096 blocks, acc[4][4] (64 AGPR) -> ~140 total regs/wave,
//    4 blocks/CU, 3-4 waves/SIMD (R2 was latency-bound at 2/SIMD)
//  - PE: chunk-owned, __sinf/__cosf (native), packed b128 LDS stores
//  - s_setprio(1) around MFMA clusters (phase diversity across 4 blocks)

#define H 256
#define MT 64
#define PE_NF 60

typedef __attribute__((ext_vector_type(8))) short s16x8;   // 8 bf16
typedef __attribute__((ext_vector_type(4))) float f32x4;   // MFMA acc

static __device__ __forceinline__ unsigned short f2bf(float v) {
  unsigned int u = __float_as_uint(v);
  return (unsigned short)((u + 0x7FFFu + ((u >> 16) & 1u)) >> 16);
}
static __device__ __forceinline__ float bf2f(unsigned short u) {
  return __uint_as_float(((unsigned int)u) << 16);
}
// swizzled 16B-chunk index within a 256-elem (32-chunk) row
static __device__ __forceinline__ int hswz(int row, int chunk) {
  return (chunk & ~7) | ((chunk ^ row) & 7);
}

// ---------------------------------------------------------------------------
// Prep: W^T bf16 (k-contiguous rows) + fp32 biases into ws. (unchanged)
// ---------------------------------------------------------------------------
__global__ __launch_bounds__(256) void prep_weights(
    const float* __restrict__ wb0, const float* __restrict__ wb1,
    const float* __restrict__ wb2, const float* __restrict__ wb3,
    const float* __restrict__ wb4,
    unsigned short* __restrict__ w0t, unsigned short* __restrict__ w14t,
    float* __restrict__ biases) {
  int z = blockIdx.z;
  int li = z >> 4, b = z & 15;
  int k0 = blockIdx.x * 32;
  int n0 = blockIdx.y * 32;
  int Ks, Kd;
  const float* src;
  unsigned short* dst;
  if (li == 0) {
    Ks = 120; Kd = 128;
    if (k0 >= 128) return;
    src = wb0 + (size_t)b * 121 * H;
    dst = w0t + (size_t)b * H * 128;
  } else {
    Ks = 256; Kd = 256;
    const float* srcs[4] = {wb1, wb2, wb3, wb4};
    src = srcs[li - 1] + (size_t)b * 257 * H;
    dst = w14t + ((size_t)(li - 1) * 16 + b) * H * 256;
  }
  __shared__ float tile[32][33];
  int tx = threadIdx.x & 31, ty0 = threadIdx.x >> 5;
#pragma unroll
  for (int i = 0; i < 4; ++i) {
    int k = k0 + ty0 + i * 8;
    tile[ty0 + i * 8][tx] = (k < Ks) ? src[(size_t)k * H + n0 + tx] : 0.f;
  }
  if (k0 == 0 && ty0 == 0)
    biases[((size_t)li * 16 + b) * H + n0 + tx] = src[(size_t)Ks * H + n0 + tx];
  __syncthreads();
#pragma unroll
  for (int i = 0; i < 4; ++i) {
    int n = n0 + ty0 + i * 8;
    dst[(size_t)n * Kd + k0 + tx] = f2bf(tile[tx][ty0 + i * 8]);
  }
}

// ---------------------------------------------------------------------------
// One fused Linear+ReLU layer (64 rows x 256 cols per block, wave w -> cols
// [w*64, w*64+64), all 64 rows).
// w_frag (A): lane holds W^T[n = w*64+ct*16+rlane][kgrp*8 + kt*32 .. +7]
// h_frag (B): lane holds h[m = rt*16+rlane][kgrp*8 + kt*32 .. +7] (swizzled)
// C (swapped): m = tile_m + (lane&15), n = tile_n + (lane>>4)*4 + reg
// ---------------------------------------------------------------------------
template <int NKT>
static __device__ __forceinline__ void mlp_layer(
    const unsigned short* __restrict__ wl, const float* __restrict__ bl,
    unsigned short* __restrict__ h_s, const int rlane, const int kgrp,
    const int w) {
  const int n_base = w * 64;

  f32x4 acc[4][4];
  {
    f32x4 bini[4];
#pragma unroll
    for (int ct = 0; ct < 4; ++ct)
      bini[ct] = *(const f32x4*)(bl + n_base + ct * 16 + kgrp * 4);
#pragma unroll
    for (int rt = 0; rt < 4; ++rt)
#pragma unroll
      for (int ct = 0; ct < 4; ++ct) acc[rt][ct] = bini[ct];
  }

  const unsigned short* wp[4];
#pragma unroll
  for (int ct = 0; ct < 4; ++ct)
    wp[ct] = wl + (size_t)(n_base + ct * 16 + rlane) * (NKT * 32) + kgrp * 8;
  int aoff[4];
#pragma unroll
  for (int rt = 0; rt < 4; ++rt) aoff[rt] = (rt * 16 + rlane) * 256;

  s16x8 bb[2][4];
#pragma unroll
  for (int ct = 0; ct < 4; ++ct) bb[0][ct] = *(const s16x8*)(wp[ct]);

#pragma unroll
  for (int kt = 0; kt < NKT; ++kt) {
    if (kt + 1 < NKT) {
#pragma unroll
      for (int ct = 0; ct < 4; ++ct)
        bb[(kt + 1) & 1][ct] = *(const s16x8*)(wp[ct] + (kt + 1) * 32);
    }
    s16x8 afr[4];
    const int cs = hswz(rlane, kt * 4 + kgrp) * 8;
#pragma unroll
    for (int rt = 0; rt < 4; ++rt)
      afr[rt] = *(const s16x8*)&h_s[aoff[rt] + cs];
    __builtin_amdgcn_s_setprio(1);
#pragma unroll
    for (int rt = 0; rt < 4; ++rt)
#pragma unroll
      for (int ct = 0; ct < 4; ++ct)
        acc[rt][ct] = __builtin_amdgcn_mfma_f32_16x16x32_bf16(
            bb[kt & 1][ct], afr[rt], acc[rt][ct], 0, 0, 0);
    __builtin_amdgcn_s_setprio(0);
  }
  __syncthreads();  // all h reads done before overwrite

  // epilogue: ReLU + pack 4 bf16 -> b64 store  (h[m][n0..n0+3])
  const int sub = (kgrp & 1) * 4;
  const int cbase = w * 8 + (kgrp >> 1);
#pragma unroll
  for (int rt = 0; rt < 4; ++rt) {
    const int m = rt * 16 + rlane;
    const int rowb = m * 256;
#pragma unroll
    for (int ct = 0; ct < 4; ++ct) {
      const int cs = hswz(m, cbase + ct * 2);
      float v0 = fmaxf(acc[rt][ct][0], 0.f);
      float v1 = fmaxf(acc[rt][ct][1], 0.f);
      float v2 = fmaxf(acc[rt][ct][2], 0.f);
      float v3 = fmaxf(acc[rt][ct][3], 0.f);
      union { __hip_bfloat162 h2[2]; uint2 u; } pk;
      pk.h2[0] = __float22bfloat162_rn(float2{v0, v1});
      pk.h2[1] = __float22bfloat162_rn(float2{v2, v3});
      *(uint2*)&h_s[rowb + cs * 8 + sub] = pk.u;
    }
  }
  __syncthreads();  // h ready for next layer / final
}

// ---------------------------------------------------------------------------
__global__ __launch_bounds__(256, 3) void hyponerf_main(
    const float* __restrict__ x, const float* __restrict__ rfreq,
    const float* __restrict__ wbout,
    const unsigned short* __restrict__ w0t, const unsigned short* __restrict__ w14t,
    const float* __restrict__ biases, float* __restrict__ out) {
  __shared__ __align__(16) unsigned short h_s[MT * 256];  // 32768 B
  __shared__ float fr_s[PE_NF * 3];
  __shared__ float x_s[MT * 3];
  __shared__ float wout_s[H + 1];

  // XCD-aware swizzle: 4096 blocks, 8 XCDs -> batches {2x,2x+1} per XCD
  int bid = blockIdx.x;
  int logical = (bid & 7) * 512 + (bid >> 3);
  int b  = logical >> 8;
  int mt = logical & 255;

  int t = threadIdx.x;
  int w = t >> 6, l = t & 63;
  int rlane = l & 15;
  int kgrp  = l >> 4;

  const float* xg = x + ((size_t)b * 16384 + (size_t)mt * MT) * 3;
  for (int i = t; i < MT * 3; i += 256) x_s[i] = xg[i];
  for (int i = t; i < PE_NF * 3; i += 256) fr_s[i] = rfreq[i] * 20.0f;
  for (int i = t; i < H + 1; i += 256) wout_s[i] = wbout[(size_t)b * (H + 1) + i];
  __syncthreads();

  // ---- Gaussian PE, chunk-owned: thread (r, q) computes n in [q*32,q*32+32)
  //   n<60: sin(k_n); 60<=n<120: cos(k_{n-60}); n>=120: 0.  b128 stores.
  {
    int r = t >> 2;          // 0..63
    int q = t & 3;           // 0..3
    float x0 = x_s[r * 3 + 0], x1 = x_s[r * 3 + 1], x2 = x_s[r * 3 + 2];
    int rowb = r * 256;
#pragma unroll
    for (int cc = 0; cc < 4; ++cc) {
      union { unsigned short us[8]; s16x8 v; } pk;
#pragma unroll
      for (int j = 0; j < 8; ++j) {
        int n = q * 32 + cc * 8 + j;
        float v = 0.f;
        if (n < 60) {
          float kv = x0 * fr_s[n * 3] + x1 * fr_s[n * 3 + 1] + x2 * fr_s[n * 3 + 2];
          v = __sinf(kv);
        } else if (n < 120) {
          int f = n - 60;
          float kv = x0 * fr_s[f * 3] + x1 * fr_s[f * 3 + 1] + x2 * fr_s[f * 3 + 2];
          v = __cosf(kv);
        }
        pk.us[j] = f2bf(v);
      }
      *(s16x8*)&h_s[rowb + hswz(r, q * 4 + cc) * 8] = pk.v;
    }
  }
  __syncthreads();

  // ---- 5 fused Linear+ReLU layers
  mlp_layer<4>(w0t + (size_t)b * H * 128, biases + (size_t)b * H, h_s,
               rlane, kgrp, w);
#pragma unroll 1
  for (int li = 1; li < 5; ++li) {
    mlp_layer<8>(w14t + ((size_t)(li - 1) * 16 + b) * H * 256,
                 biases + ((size_t)li * 16 + b) * H, h_s, rlane, kgrp, w);
  }

  // ---- final projection: out[r] = h[r][:] . wout + bias_out
  {
    int r = t >> 2;          // 0..63
    int q = t & 3;           // chunk group: chunks q*8 .. q*8+7
    int rowb = r * 256;
    float sum = 0.f;
#pragma unroll
    for (int c = 0; c < 8; ++c) {
      int ch = q * 8 + c;
      const s16x8 hv = *(const s16x8*)&h_s[rowb + hswz(r, ch) * 8];
#pragma unroll
      for (int j = 0; j < 8; ++j)
        sum += bf2f((unsigned short)hv[j]) * wout_s[ch * 8 + j];
    }
    sum += __shfl_xor(sum, 1);
    sum += __shfl_xor(sum, 2);
    if (q == 0)
      out[(size_t)b * 16384 + (size_t)mt * MT + r] = sum + wout_s[H];
  }
}

// ---------------------------------------------------------------------------
extern "C" void kernel_launch(void* const* d_in, const int* in_sizes, int n_in,
                              void* d_out, int out_size, void* d_ws, size_t ws_size,
                              hipStream_t stream) {
  const float* x     = (const float*)d_in[0];
  const float* wb0   = (const float*)d_in[1];
  const float* wb1   = (const float*)d_in[2];
  const float* wb2   = (const float*)d_in[3];
  const float* wb3   = (const float*)d_in[4];
  const float* wb4   = (const float*)d_in[5];
  const float* wbout = (const float*)d_in[6];
  const float* rfreq = (const float*)d_in[7];
  float* out = (float*)d_out;

  char* ws = (char*)d_ws;
  unsigned short* w0t  = (unsigned short*)ws;                                // [16][256][128]
  unsigned short* w14t = (unsigned short*)(ws + (size_t)16 * 256 * 128 * 2); // [4][16][256][256]
  float* biases = (float*)(ws + (size_t)16 * 256 * 128 * 2
                              + (size_t)4 * 16 * 256 * 256 * 2);             // [5][16][256]

  prep_weights<<<dim3(8, 8, 80), 256, 0, stream>>>(wb0, wb1, wb2, wb3, wb4,
                                                   w0t, w14t, biases);
  hyponerf_main<<<dim3(4096), 256, 0, stream>>>(x, rfreq, wbout, w0t, w14t,
                                                biases, out);
}

// Round 4
// 173.329 us; speedup vs baseline: 1.6992x; 1.6992x over previous
//
#include <hip/hip_runtime.h>
#include <hip/hip_bf16.h>

// HypoNerf fused MLP on MI355X (gfx950). R4:
//  - weights pre-packed in MFMA *fragment order*: each wave's (kt,ct) B-frag
//    is one contiguous 1KB block -> coalesced streams, kills the 300x L2-miss
//    amplification seen in R1-R3 (FETCH_SIZE 6-8 GB vs 25 MB unique)
//  - cross-layer prefetch: next layer's kt=0 frags issue during current
//    layer's last K-step; layer0's frags issue before the PE phase
//  - otherwise R2 config (MT=128, 4 waves, 2 blocks/CU, swizzled h in LDS)

#define H 256
#define MT 128
#define PE_NF 60

typedef __attribute__((ext_vector_type(8))) short s16x8;   // 8 bf16
typedef __attribute__((ext_vector_type(4))) float f32x4;   // MFMA acc

static __device__ __forceinline__ unsigned short f2bf(float v) {
  unsigned int u = __float_as_uint(v);
  return (unsigned short)((u + 0x7FFFu + ((u >> 16) & 1u)) >> 16);
}
static __device__ __forceinline__ float bf2f(unsigned short u) {
  return __uint_as_float(((unsigned int)u) << 16);
}
// swizzled 16B-chunk index within a 256-elem (32-chunk) row
static __device__ __forceinline__ int hswz(int row, int chunk) {
  return (chunk & ~7) | ((chunk ^ row) & 7);
}

// ---------------------------------------------------------------------------
// Prep: wb (fp32, [K+1][H] row-major, last row bias) -> fragment-packed bf16.
// pack elem idx for (n, k):  (kt*16 + w*4 + ct)*512 + (kgrp*16 + rlane)*8 + j
//   where kt=k>>5, kgrp=(k>>3)&3, j=k&7, w=n>>6, ct=(n>>4)&3, rlane=n&15.
// Lane l of wave w then loads frag(kt,ct) at base + (kt*16+w*4+ct)*512 + l*8,
// receiving exactly W^T[w*64+ct*16+(l&15)][kt*32+(l>>4)*8 .. +7] (== R2 frag).
// ---------------------------------------------------------------------------
__global__ __launch_bounds__(256) void prep_weights(
    const float* __restrict__ wb0, const float* __restrict__ wb1,
    const float* __restrict__ wb2, const float* __restrict__ wb3,
    const float* __restrict__ wb4,
    unsigned short* __restrict__ w0p, unsigned short* __restrict__ w14p,
    float* __restrict__ biases) {
  int z = blockIdx.z;
  int li = z >> 4, b = z & 15;
  int k0 = blockIdx.x * 32;   // one kt chunk per block
  int n0 = blockIdx.y * 32;
  int Ks;
  const float* src;
  unsigned short* dst;
  if (li == 0) {
    Ks = 120;
    if (k0 >= 128) return;
    src = wb0 + (size_t)b * 121 * H;
    dst = w0p + (size_t)b * 32768;
  } else {
    Ks = 256;
    const float* srcs[4] = {wb1, wb2, wb3, wb4};
    src = srcs[li - 1] + (size_t)b * 257 * H;
    dst = w14p + ((size_t)(li - 1) * 16 + b) * 65536;
  }
  __shared__ float tile[32][33];
  int t = threadIdx.x;
  int tx = t & 31, ty = t >> 5;
#pragma unroll
  for (int i = 0; i < 4; ++i) {
    int k = k0 + ty + i * 8;
    tile[ty + i * 8][tx] = (k < Ks) ? src[(size_t)k * H + n0 + tx] : 0.f;
  }
  if (k0 == 0 && ty == 0)
    biases[((size_t)li * 16 + b) * H + n0 + tx] = src[(size_t)Ks * H + n0 + tx];
  __syncthreads();
  if (t < 128) {
    int nn = t & 31, kg = t >> 5;      // kg = kgrp 0..3
    int n = n0 + nn;
    int kt = k0 >> 5;
    int w = n >> 6, ct = (n >> 4) & 3, rl = n & 15;
    union { unsigned short us[8]; s16x8 v; } pk;
#pragma unroll
    for (int j = 0; j < 8; ++j) pk.us[j] = f2bf(tile[kg * 8 + j][nn]);
    *(s16x8*)&dst[(size_t)(kt * 16 + w * 4 + ct) * 512 + (kg * 16 + rl) * 8] = pk.v;
  }
}

// ---------------------------------------------------------------------------
// One fused Linear+ReLU layer (128 rows x 256 cols; wave w -> cols
// [w*64, w*64+64)).  bb[2][4] is the caller-persistent B-frag ping-pong:
// on entry bb[0] holds this layer's kt=0 frags; on exit (non-LAST) bb[0]
// holds the NEXT layer's kt=0 frags (in flight across the epilogue).
// ---------------------------------------------------------------------------
template <int NKT, bool LAST>
static __device__ __forceinline__ void mlp_layer(
    const unsigned short* __restrict__ wl, const unsigned short* __restrict__ wln,
    const float* __restrict__ bl, unsigned short* __restrict__ h_s,
    const int rlane, const int kgrp, const int w, const int l,
    s16x8 (&bb)[2][4]) {
  static_assert((NKT & 1) == 0, "ping-pong parity needs even NKT");
  const int n_base = w * 64;

  f32x4 acc[8][4];
  {
    f32x4 bini[4];
#pragma unroll
    for (int ct = 0; ct < 4; ++ct)
      bini[ct] = *(const f32x4*)(bl + n_base + ct * 16 + kgrp * 4);
#pragma unroll
    for (int rt = 0; rt < 8; ++rt)
#pragma unroll
      for (int ct = 0; ct < 4; ++ct) acc[rt][ct] = bini[ct];
  }

  const unsigned short* fp = wl + (size_t)(w * 4) * 512 + l * 8;
  int aoff[8];
#pragma unroll
  for (int rt = 0; rt < 8; ++rt) aoff[rt] = (rt * 16 + rlane) * 256;

#pragma unroll
  for (int kt = 0; kt < NKT; ++kt) {
    if (kt + 1 < NKT) {
#pragma unroll
      for (int ct = 0; ct < 4; ++ct)
        bb[(kt + 1) & 1][ct] = *(const s16x8*)(fp + (kt + 1) * 8192 + ct * 512);
    } else if (!LAST) {
      const unsigned short* fpn = wln + (size_t)(w * 4) * 512 + l * 8;
#pragma unroll
      for (int ct = 0; ct < 4; ++ct)
        bb[0][ct] = *(const s16x8*)(fpn + ct * 512);   // NKT even -> slot 0
    }
    s16x8 afr[8];
    const int cs = hswz(rlane, kt * 4 + kgrp) * 8;
#pragma unroll
    for (int rt = 0; rt < 8; ++rt)
      afr[rt] = *(const s16x8*)&h_s[aoff[rt] + cs];
    __builtin_amdgcn_s_setprio(1);
#pragma unroll
    for (int rt = 0; rt < 8; ++rt)
#pragma unroll
      for (int ct = 0; ct < 4; ++ct)
        acc[rt][ct] = __builtin_amdgcn_mfma_f32_16x16x32_bf16(
            bb[kt & 1][ct], afr[rt], acc[rt][ct], 0, 0, 0);
    __builtin_amdgcn_s_setprio(0);
  }
  __syncthreads();  // all h reads done before overwrite

  // epilogue: ReLU + pack 4 bf16 -> b64 store  (h[m][n0..n0+3])
  const int sub = (kgrp & 1) * 4;
  const int cbase = w * 8 + (kgrp >> 1);
#pragma unroll
  for (int rt = 0; rt < 8; ++rt) {
    const int m = rt * 16 + rlane;
    const int rowb = m * 256;
#pragma unroll
    for (int ct = 0; ct < 4; ++ct) {
      const int cs = hswz(m, cbase + ct * 2);
      float v0 = fmaxf(acc[rt][ct][0], 0.f);
      float v1 = fmaxf(acc[rt][ct][1], 0.f);
      float v2 = fmaxf(acc[rt][ct][2], 0.f);
      float v3 = fmaxf(acc[rt][ct][3], 0.f);
      union { __hip_bfloat162 h2[2]; uint2 u; } pk;
      pk.h2[0] = __float22bfloat162_rn(float2{v0, v1});
      pk.h2[1] = __float22bfloat162_rn(float2{v2, v3});
      *(uint2*)&h_s[rowb + cs * 8 + sub] = pk.u;
    }
  }
  __syncthreads();  // h ready for next layer / final
}

// ---------------------------------------------------------------------------
__global__ __launch_bounds__(256, 2) void hyponerf_main(
    const float* __restrict__ x, const float* __restrict__ rfreq,
    const float* __restrict__ wbout,
    const unsigned short* __restrict__ w0p, const unsigned short* __restrict__ w14p,
    const float* __restrict__ biases, float* __restrict__ out) {
  __shared__ __align__(16) unsigned short h_s[MT * 256];  // 65536 B
  __shared__ float fr_s[PE_NF * 3];
  __shared__ float x_s[MT * 3];
  __shared__ float wout_s[H + 1];

  // XCD-aware swizzle: 2048 blocks, 8 XCDs -> contiguous batches per XCD
  int bid = blockIdx.x;
  int logical = (bid & 7) * 256 + (bid >> 3);
  int b  = logical >> 7;
  int mt = logical & 127;

  int t = threadIdx.x;
  int w = t >> 6, l = t & 63;
  int rlane = l & 15;
  int kgrp  = l >> 4;

  const unsigned short* wl0 = w0p + (size_t)b * 32768;
  const unsigned short* wl1 = w14p + (size_t)(0 * 16 + b) * 65536;
  const unsigned short* wl2 = w14p + (size_t)(1 * 16 + b) * 65536;
  const unsigned short* wl3 = w14p + (size_t)(2 * 16 + b) * 65536;
  const unsigned short* wl4 = w14p + (size_t)(3 * 16 + b) * 65536;

  // issue layer0 kt=0 B-frags NOW; latency hides under staging + PE
  s16x8 bb[2][4];
  {
    const unsigned short* fp0 = wl0 + (size_t)(w * 4) * 512 + l * 8;
#pragma unroll
    for (int ct = 0; ct < 4; ++ct) bb[0][ct] = *(const s16x8*)(fp0 + ct * 512);
  }

  const float* xg = x + ((size_t)b * 16384 + (size_t)mt * MT) * 3;
  for (int i = t; i < MT * 3; i += 256) x_s[i] = xg[i];
  for (int i = t; i < PE_NF * 3; i += 256) fr_s[i] = rfreq[i] * 20.0f;
  for (int i = t; i < H + 1; i += 256) wout_s[i] = wbout[(size_t)b * (H + 1) + i];
  __syncthreads();

  // ---- Gaussian PE, chunk-owned b128 stores: thread (r = t>>1, q = t&1)
  //   covers n in [q*64, q*64+64): n<60 sin, 60..119 cos(n-60), 120..127 0.
  {
    int r = t >> 1;
    int q = t & 1;
    float x0 = x_s[r * 3 + 0], x1 = x_s[r * 3 + 1], x2 = x_s[r * 3 + 2];
    int rowb = r * 256;
#pragma unroll
    for (int cc = 0; cc < 8; ++cc) {
      union { unsigned short us[8]; s16x8 v; } pk;
#pragma unroll
      for (int j = 0; j < 8; ++j) {
        int n = q * 64 + cc * 8 + j;
        float v = 0.f;
        if (n < 60) {
          float kv = x0 * fr_s[n * 3] + x1 * fr_s[n * 3 + 1] + x2 * fr_s[n * 3 + 2];
          v = __sinf(kv);
        } else if (n < 120) {
          int f = n - 60;
          float kv = x0 * fr_s[f * 3] + x1 * fr_s[f * 3 + 1] + x2 * fr_s[f * 3 + 2];
          v = __cosf(kv);
        }
        pk.us[j] = f2bf(v);
      }
      *(s16x8*)&h_s[rowb + hswz(r, q * 8 + cc) * 8] = pk.v;
    }
  }
  __syncthreads();

  // ---- 5 fused Linear+ReLU layers (bb carries next layer's kt=0 frags)
  mlp_layer<4, false>(wl0, wl1, biases + (size_t)(0 * 16 + b) * H, h_s,
                      rlane, kgrp, w, l, bb);
  mlp_layer<8, false>(wl1, wl2, biases + (size_t)(1 * 16 + b) * H, h_s,
                      rlane, kgrp, w, l, bb);
  mlp_layer<8, false>(wl2, wl3, biases + (size_t)(2 * 16 + b) * H, h_s,
                      rlane, kgrp, w, l, bb);
  mlp_layer<8, false>(wl3, wl4, biases + (size_t)(3 * 16 + b) * H, h_s,
                      rlane, kgrp, w, l, bb);
  mlp_layer<8, true >(wl4, wl4, biases + (size_t)(4 * 16 + b) * H, h_s,
                      rlane, kgrp, w, l, bb);

  // ---- final projection: out[r] = h[r][:] . wout + bias_out
  {
    int r = t >> 1;
    int cb = (t & 1) * 16;
    int rowb = r * 256;
    float sum = 0.f;
#pragma unroll
    for (int c = 0; c < 16; ++c) {
      int ch = cb + c;
      const s16x8 hv = *(const s16x8*)&h_s[rowb + hswz(r, ch) * 8];
#pragma unroll
      for (int j = 0; j < 8; ++j)
        sum += bf2f((unsigned short)hv[j]) * wout_s[ch * 8 + j];
    }
    sum += __shfl_xor(sum, 1);
    if ((t & 1) == 0)
      out[(size_t)b * 16384 + (size_t)mt * MT + r] = sum + wout_s[H];
  }
}

// ---------------------------------------------------------------------------
extern "C" void kernel_launch(void* const* d_in, const int* in_sizes, int n_in,
                              void* d_out, int out_size, void* d_ws, size_t ws_size,
                              hipStream_t stream) {
  const float* x     = (const float*)d_in[0];
  const float* wb0   = (const float*)d_in[1];
  const float* wb1   = (const float*)d_in[2];
  const float* wb2   = (const float*)d_in[3];
  const float* wb3   = (const float*)d_in[4];
  const float* wb4   = (const float*)d_in[5];
  const float* wbout = (const float*)d_in[6];
  const float* rfreq = (const float*)d_in[7];
  float* out = (float*)d_out;

  char* ws = (char*)d_ws;
  unsigned short* w0p  = (unsigned short*)ws;                                // 16 x 32768 bf16
  unsigned short* w14p = (unsigned short*)(ws + (size_t)16 * 32768 * 2);     // 64 x 65536 bf16
  float* biases = (float*)(ws + (size_t)16 * 32768 * 2
                              + (size_t)64 * 65536 * 2);                     // [5][16][256] f32

  prep_weights<<<dim3(8, 8, 80), 256, 0, stream>>>(wb0, wb1, wb2, wb3, wb4,
                                                   w0p, w14p, biases);
  hyponerf_main<<<dim3(2048), 256, 0, stream>>>(x, rfreq, wbout, w0p, w14p,
                                                biases, out);
}